// Round 1
// baseline (521.572 us; speedup 1.0000x reference)
//
#include <hip/hip_runtime.h>

#define B_  2
#define S_  2048
#define E_  2048
#define H_  16
#define D_  128
#define BS_ (B_*S_)

typedef __bf16 bf16_t;
typedef __bf16 bf16x8 __attribute__((ext_vector_type(8)));
typedef __bf16 bf16x4 __attribute__((ext_vector_type(4)));
typedef float  f32x4  __attribute__((ext_vector_type(4)));

// ---------------- fp32 -> bf16 convert ----------------
__global__ void cvt_f32_bf16(const float* __restrict__ in, bf16_t* __restrict__ out, int n) {
    int i = (blockIdx.x * blockDim.x + threadIdx.x) * 4;
    if (i < n) {
        float4 v = *(const float4*)(in + i);
        bf16x4 o;
        o[0] = (bf16_t)v.x; o[1] = (bf16_t)v.y; o[2] = (bf16_t)v.z; o[3] = (bf16_t)v.w;
        *(bf16x4*)(out + i) = o;
    }
}

// ---------------- C[M,N] = A[M,K] @ W[N,K]^T + bias ----------------
// A, W bf16 row-major. Output fp32 (Cf) or bf16 (Cb). 128x128 tile, BK=64,
// 4 waves each 64x64 via 4x4 mfma_f32_16x16x32_bf16.
// Fragment layouts (m89/m91/m120-verified):
//   A-frag: lane l holds A[m=l&15][k=(l>>4)*8+j]
//   B-frag: lane l holds B[k=(l>>4)*8+j][n=l&15]  (B = W^T, so read W[n][k] contiguous)
//   C/D   : lane l reg r -> row=(l>>4)*4+r, col=l&15
__global__ __launch_bounds__(256) void gemm_bt(
    const bf16_t* __restrict__ A, const bf16_t* __restrict__ W,
    const float* __restrict__ bias,
    float* __restrict__ Cf, bf16_t* __restrict__ Cb,
    int M, int N, int K)
{
    __shared__ __align__(16) bf16_t As[128][72];  // pad 64->72: 144B row stride, 16B-aligned, bank-friendly
    __shared__ __align__(16) bf16_t Bs[128][72];

    const int tid  = threadIdx.x;
    const int wave = tid >> 6, lane = tid & 63;
    const int wm = wave >> 1, wn = wave & 1;
    const int lrow = lane & 15, quad = lane >> 4;
    const int m0 = blockIdx.y * 128, n0 = blockIdx.x * 128;
    const int sr  = tid >> 3;         // 0..31
    const int scc = (tid & 7) << 3;   // 0..56 step 8

    f32x4 acc[4][4] = {};

    for (int k0 = 0; k0 < K; k0 += 64) {
        __syncthreads();
#pragma unroll
        for (int i = 0; i < 4; ++i) {
            int rr = sr + i * 32;
            *(uint4*)&As[rr][scc] = *(const uint4*)(A + (size_t)(m0 + rr) * K + k0 + scc);
            *(uint4*)&Bs[rr][scc] = *(const uint4*)(W + (size_t)(n0 + rr) * K + k0 + scc);
        }
        __syncthreads();
#pragma unroll
        for (int ks = 0; ks < 2; ++ks) {
            bf16x8 af[4], bfr[4];
#pragma unroll
            for (int mt = 0; mt < 4; ++mt)
                af[mt] = *(const bf16x8*)&As[wm * 64 + mt * 16 + lrow][ks * 32 + quad * 8];
#pragma unroll
            for (int nt = 0; nt < 4; ++nt)
                bfr[nt] = *(const bf16x8*)&Bs[wn * 64 + nt * 16 + lrow][ks * 32 + quad * 8];
#pragma unroll
            for (int mt = 0; mt < 4; ++mt)
#pragma unroll
                for (int nt = 0; nt < 4; ++nt)
                    acc[mt][nt] = __builtin_amdgcn_mfma_f32_16x16x32_bf16(
                        af[mt], bfr[nt], acc[mt][nt], 0, 0, 0);
        }
    }

#pragma unroll
    for (int mt = 0; mt < 4; ++mt) {
#pragma unroll
        for (int nt = 0; nt < 4; ++nt) {
#pragma unroll
            for (int r = 0; r < 4; ++r) {
                int row = m0 + wm * 64 + mt * 16 + quad * 4 + r;
                int col = n0 + wn * 64 + nt * 16 + lrow;
                float v = acc[mt][nt][r] + bias[col];
                if (Cf) Cf[(size_t)row * N + col] = v;
                else    Cb[(size_t)row * N + col] = (bf16_t)v;
            }
        }
    }
}

// ---------------- flash-style causal MQA attention ----------------
// Q: [B,S,H,D] bf16  (== [B,S,E] from Q projection)
// K, V: [B,S,D] bf16 (single KV head)
// O: [B,S,H,D] bf16
// Block: 256 threads = 4 waves; handles 64 Q rows of one (b,h).
// Each wave owns 16 Q rows; iterates 64-key tiles up to causal bound.
__global__ __launch_bounds__(256) void mqa_attn(
    const bf16_t* __restrict__ Q, const bf16_t* __restrict__ K,
    const bf16_t* __restrict__ V, bf16_t* __restrict__ O)
{
    __shared__ __align__(16) bf16_t Kt[64][136];   // K-tile [key][d], pad for banks
    __shared__ __align__(16) bf16_t Vt[128][72];   // V-tile transposed [d][key]
    __shared__ __align__(16) bf16_t Pl[4][16][72]; // per-wave P round-trip (C-layout -> A-layout)

    const int qb = blockIdx.x, h = blockIdx.y, b = blockIdx.z;
    const int tid = threadIdx.x, wave = tid >> 6, lane = tid & 63;
    const int lrow = lane & 15, quad = lane >> 4;
    const int q_base = qb * 64;

    // Q fragments for this wave's 16 rows, 4 K-steps of 32 (D=128), held in regs
    bf16x8 qf[4];
    {
        const bf16_t* qp = Q + ((size_t)(b * S_ + q_base + wave * 16 + lrow)) * E_ + h * D_ + quad * 8;
#pragma unroll
        for (int ks = 0; ks < 4; ++ks) qf[ks] = *(const bf16x8*)(qp + ks * 32);
    }

    f32x4 oacc[8] = {};          // O accumulator, 16 rows x 128 d in C-layout
    float m_r[4], l_r[4];
#pragma unroll
    for (int r = 0; r < 4; ++r) { m_r[r] = -1e30f; l_r[r] = 0.f; }

    const int ntiles = qb + 1;
    for (int kt = 0; kt < ntiles; ++kt) {
        const int k_base = kt * 64;
        __syncthreads();  // prior iteration's Kt/Vt reads complete
        // stage K-tile: 64 x 128 bf16, 16B chunks
#pragma unroll
        for (int i = 0; i < 4; ++i) {
            int c = tid + 256 * i;
            int rr = c >> 4, cc = (c & 15) << 3;
            *(uint4*)&Kt[rr][cc] = *(const uint4*)(K + ((size_t)(b * S_ + k_base + rr)) * D_ + cc);
        }
        // stage V-tile transposed: read [n][d] 16B, scatter to Vt[d][n]
#pragma unroll
        for (int i = 0; i < 4; ++i) {
            int c = tid + 256 * i;
            int n = c & 63, d0 = (c >> 6) << 3;
            bf16x8 v = *(const bf16x8*)(V + ((size_t)(b * S_ + k_base + n)) * D_ + d0);
#pragma unroll
            for (int j = 0; j < 8; ++j) Vt[d0 + j][n] = v[j];
        }
        __syncthreads();

        // S = Q K^T : 16x64 per wave, 4 col-tiles x 4 K-steps
        f32x4 sc[4] = {};
#pragma unroll
        for (int ks = 0; ks < 4; ++ks) {
            bf16x8 a = qf[ks];
#pragma unroll
            for (int c = 0; c < 4; ++c) {
                bf16x8 kb = *(const bf16x8*)&Kt[c * 16 + lrow][ks * 32 + quad * 8];
                sc[c] = __builtin_amdgcn_mfma_f32_16x16x32_bf16(a, kb, sc[c], 0, 0, 0);
            }
        }

        // scale + causal mask (only diagonal tile needs masking)
        const bool diag = (kt == qb);
        float mx[4];
#pragma unroll
        for (int r = 0; r < 4; ++r) mx[r] = -1e30f;
#pragma unroll
        for (int c = 0; c < 4; ++c) {
#pragma unroll
            for (int r = 0; r < 4; ++r) {
                float s = sc[c][r] * 0.08838834764831845f; // 1/sqrt(128)
                if (diag) {
                    int kj = k_base + c * 16 + lrow;
                    int qi = q_base + wave * 16 + quad * 4 + r;
                    if (kj > qi) s = -1e30f;
                }
                sc[c][r] = s;
                mx[r] = fmaxf(mx[r], s);
            }
        }
        // row-max across the 16 lanes holding this row's columns
#pragma unroll
        for (int off = 8; off >= 1; off >>= 1)
#pragma unroll
            for (int r = 0; r < 4; ++r) mx[r] = fmaxf(mx[r], __shfl_xor(mx[r], off, 16));

        float al[4], rs[4];
#pragma unroll
        for (int r = 0; r < 4; ++r) {
            float mn = fmaxf(m_r[r], mx[r]);
            al[r] = __expf(m_r[r] - mn);
            m_r[r] = mn;
            rs[r] = 0.f;
        }
#pragma unroll
        for (int c = 0; c < 4; ++c)
#pragma unroll
            for (int r = 0; r < 4; ++r) {
                float pv = __expf(sc[c][r] - m_r[r]);
                sc[c][r] = pv;
                rs[r] += pv;
            }
#pragma unroll
        for (int off = 8; off >= 1; off >>= 1)
#pragma unroll
            for (int r = 0; r < 4; ++r) rs[r] += __shfl_xor(rs[r], off, 16);
#pragma unroll
        for (int r = 0; r < 4; ++r) l_r[r] = l_r[r] * al[r] + rs[r];
        // rescale O accumulator
#pragma unroll
        for (int dt = 0; dt < 8; ++dt)
#pragma unroll
            for (int r = 0; r < 4; ++r) oacc[dt][r] *= al[r];

        // P: C-layout -> LDS -> A-layout
#pragma unroll
        for (int c = 0; c < 4; ++c)
#pragma unroll
            for (int r = 0; r < 4; ++r)
                Pl[wave][quad * 4 + r][c * 16 + lrow] = (bf16_t)sc[c][r];
        __syncthreads();

        // O += P @ V : 16x128, 8 d-tiles x 2 K-steps over 64 keys
#pragma unroll
        for (int ks = 0; ks < 2; ++ks) {
            bf16x8 ap = *(const bf16x8*)&Pl[wave][lrow][ks * 32 + quad * 8];
#pragma unroll
            for (int dt = 0; dt < 8; ++dt) {
                bf16x8 bv = *(const bf16x8*)&Vt[dt * 16 + lrow][ks * 32 + quad * 8];
                oacc[dt] = __builtin_amdgcn_mfma_f32_16x16x32_bf16(ap, bv, oacc[dt], 0, 0, 0);
            }
        }
    }

    // epilogue: normalize and store
#pragma unroll
    for (int r = 0; r < 4; ++r) {
        float inv = 1.0f / l_r[r];
        int row = q_base + wave * 16 + quad * 4 + r;
#pragma unroll
        for (int dt = 0; dt < 8; ++dt)
            O[((size_t)(b * S_ + row)) * E_ + h * D_ + dt * 16 + lrow] = (bf16_t)(oacc[dt][r] * inv);
    }
}

// ---------------- launch ----------------
extern "C" void kernel_launch(void* const* d_in, const int* in_sizes, int n_in,
                              void* d_out, int out_size, void* d_ws, size_t ws_size,
                              hipStream_t stream)
{
    const float* x   = (const float*)d_in[0];
    const float* kv  = (const float*)d_in[1];
    const float* Wq  = (const float*)d_in[2];
    const float* bq  = (const float*)d_in[3];
    const float* Wk  = (const float*)d_in[4];
    const float* bk  = (const float*)d_in[5];
    const float* Wv  = (const float*)d_in[6];
    const float* bv  = (const float*)d_in[7];
    const float* Wo  = (const float*)d_in[8];
    const float* bo  = (const float*)d_in[9];
    float* out = (float*)d_out;

    bf16_t* p   = (bf16_t*)d_ws;
    bf16_t* xb  = p;  p += (size_t)BS_ * E_;
    bf16_t* kvb = p;  p += (size_t)BS_ * E_;
    bf16_t* Wqb = p;  p += (size_t)E_ * E_;
    bf16_t* Wkb = p;  p += (size_t)D_ * E_;
    bf16_t* Wvb = p;  p += (size_t)D_ * E_;
    bf16_t* Wob = p;  p += (size_t)E_ * E_;
    bf16_t* Qb  = p;  p += (size_t)BS_ * E_;
    bf16_t* Kb  = p;  p += (size_t)BS_ * D_;
    bf16_t* Vb  = p;  p += (size_t)BS_ * D_;
    bf16_t* Ob  = p;  p += (size_t)BS_ * E_;
    // total ws: ~87 MB

    auto cvt = [&](const float* src, bf16_t* dst, int n) {
        cvt_f32_bf16<<<dim3((n / 4 + 255) / 256), dim3(256), 0, stream>>>(src, dst, n);
    };
    cvt(x,  xb,  BS_ * E_);
    cvt(kv, kvb, BS_ * E_);
    cvt(Wq, Wqb, E_ * E_);
    cvt(Wk, Wkb, D_ * E_);
    cvt(Wv, Wvb, D_ * E_);
    cvt(Wo, Wob, E_ * E_);

    // projections
    gemm_bt<<<dim3(E_ / 128, BS_ / 128), 256, 0, stream>>>(xb,  Wqb, bq, nullptr, Qb, BS_, E_, E_);
    gemm_bt<<<dim3(1,        BS_ / 128), 256, 0, stream>>>(kvb, Wkb, bk, nullptr, Kb, BS_, D_, E_);
    gemm_bt<<<dim3(1,        BS_ / 128), 256, 0, stream>>>(kvb, Wvb, bv, nullptr, Vb, BS_, D_, E_);

    // attention
    mqa_attn<<<dim3(S_ / 64, H_, B_), 256, 0, stream>>>(Qb, Kb, Vb, Ob);

    // output projection (fp32 out)
    gemm_bt<<<dim3(E_ / 128, BS_ / 128), 256, 0, stream>>>(Ob, Wob, bo, out, nullptr, BS_, E_, E_);
}

// Round 2
// 426.158 us; speedup vs baseline: 1.2239x; 1.2239x over previous
//
#include <hip/hip_runtime.h>

#define B_  2
#define S_  2048
#define E_  2048
#define H_  16
#define D_  128
#define BS_ (B_*S_)

typedef __bf16 bf16_t;
typedef __bf16 bf16x8 __attribute__((ext_vector_type(8)));
typedef __bf16 bf16x4 __attribute__((ext_vector_type(4)));
typedef float  f32x4  __attribute__((ext_vector_type(4)));

// combined softmax scale: 1/sqrt(128) * log2(e), folded into Q projection
#define QSCALE 0.1275174131003543f

// ---------------- async global->LDS, 16B per lane per call ----------------
__device__ __forceinline__ void gld16(const bf16_t* g, bf16_t* l) {
    __builtin_amdgcn_global_load_lds(
        (const __attribute__((address_space(1))) void*)g,
        (__attribute__((address_space(3))) void*)l,
        16, 0, 0);
}

// ---------------- fused fp32 -> bf16 convert (all 6 tensors) ----------------
// segment prefix sums are compile-time: x(8388608) kv(8388608) Wq(4194304)
// Wk(262144) Wv(262144) Wo(4194304), total 25690112 = 1024*25088
__global__ void cvt_all(const float* __restrict__ s0, const float* __restrict__ s1,
                        const float* __restrict__ s2, const float* __restrict__ s3,
                        const float* __restrict__ s4, const float* __restrict__ s5,
                        bf16_t* d0, bf16_t* d1, bf16_t* d2,
                        bf16_t* d3, bf16_t* d4, bf16_t* d5)
{
    long i = ((long)blockIdx.x * blockDim.x + threadIdx.x) * 4;
    const float* s; bf16_t* d;
    if      (i <  8388608) { s = s0; d = d0; }
    else if (i < 16777216) { s = s1; d = d1; i -=  8388608; }
    else if (i < 20971520) { s = s2; d = d2; i -= 16777216; }
    else if (i < 21233664) { s = s3; d = d3; i -= 20971520; }
    else if (i < 21495808) { s = s4; d = d4; i -= 21233664; }
    else                   { s = s5; d = d5; i -= 21495808; }
    float4 v = *(const float4*)(s + i);
    bf16x4 o;
    o[0] = (bf16_t)v.x; o[1] = (bf16_t)v.y; o[2] = (bf16_t)v.z; o[3] = (bf16_t)v.w;
    *(bf16x4*)(d + i) = o;
}

// ---------------- C[M,N] = (A[M,K] @ W[N,K]^T + bias) * scale ----------------
// m97 structure: 128x128 tile, BK=64, UNPADDED LDS + global_load_lds width 16.
// dual bias: col<128 -> biasA[col], else biasB[col-128] (for fused KV proj).
__global__ __launch_bounds__(256) void gemm_bt(
    const bf16_t* __restrict__ A, const bf16_t* __restrict__ W,
    const float* __restrict__ biasA, const float* __restrict__ biasB,
    float* __restrict__ Cf, bf16_t* __restrict__ Cb,
    int M, int N, int K, float scale)
{
    __shared__ __align__(16) bf16_t As[128 * 64];   // unpadded: global_load_lds layout
    __shared__ __align__(16) bf16_t Bs[128 * 64];

    const int tid  = threadIdx.x;
    const int wave = tid >> 6, lane = tid & 63;
    const int wm = wave >> 1, wn = wave & 1;
    const int lrow = lane & 15, quad = lane >> 4;
    const int m0 = blockIdx.y * 128, n0 = blockIdx.x * 128;
    const int r8 = lane >> 3, c8 = (lane & 7) << 3;  // within-call lane->row/col

    f32x4 acc[4][4] = {};

    for (int k0 = 0; k0 < K; k0 += 64) {
        __syncthreads();
        // each wave stages 4 KB of A and 4 KB of B: 4 calls each, 1 KB/call (8 rows)
#pragma unroll
        for (int j = 0; j < 4; ++j) {
            int base = (wave * 4 + j) * 8;                  // row base, wave-uniform
            gld16(A + (size_t)(m0 + base + r8) * K + k0 + c8, &As[base * 64]);
            gld16(W + (size_t)(n0 + base + r8) * K + k0 + c8, &Bs[base * 64]);
        }
        __syncthreads();   // compiler drains vmcnt before s_barrier
#pragma unroll
        for (int ks = 0; ks < 2; ++ks) {
            bf16x8 af[4], bfr[4];
#pragma unroll
            for (int mt = 0; mt < 4; ++mt)
                af[mt] = *(const bf16x8*)&As[(wm * 64 + mt * 16 + lrow) * 64 + ks * 32 + quad * 8];
#pragma unroll
            for (int nt = 0; nt < 4; ++nt)
                bfr[nt] = *(const bf16x8*)&Bs[(wn * 64 + nt * 16 + lrow) * 64 + ks * 32 + quad * 8];
#pragma unroll
            for (int mt = 0; mt < 4; ++mt)
#pragma unroll
                for (int nt = 0; nt < 4; ++nt)
                    acc[mt][nt] = __builtin_amdgcn_mfma_f32_16x16x32_bf16(
                        af[mt], bfr[nt], acc[mt][nt], 0, 0, 0);
        }
    }

#pragma unroll
    for (int mt = 0; mt < 4; ++mt) {
#pragma unroll
        for (int nt = 0; nt < 4; ++nt) {
            int col = n0 + wn * 64 + nt * 16 + lrow;
            const float* bp = biasA; int ci = col;
            if (biasB && col >= 128) { bp = biasB; ci = col - 128; }
            float bv = bp[ci];
#pragma unroll
            for (int r = 0; r < 4; ++r) {
                int row = m0 + wm * 64 + mt * 16 + quad * 4 + r;
                float v = (acc[mt][nt][r] + bv) * scale;
                if (Cf) Cf[(size_t)row * N + col] = v;
                else    Cb[(size_t)row * N + col] = (bf16_t)v;
            }
        }
    }
}

// ---------------- flash-style causal MQA attention ----------------
// Q: [B,S,H,D] bf16, PRE-SCALED by 1/sqrt(D)*log2(e)  (exp2-domain scores)
// KV: [B,S,256] bf16 interleaved: K at col 0..127, V at col 128..255
// O: [B,S,H,D] bf16
// Block: 512 threads = 8 waves, 128 Q rows of one (b,h); wave owns 16 rows.
// No-max-subtraction online softmax (scores are O(1); clamp guards overflow);
// per-row sum reduced once in epilogue.
__global__ __launch_bounds__(512, 4) void mqa_attn(
    const bf16_t* __restrict__ Q, const bf16_t* __restrict__ KV,
    bf16_t* __restrict__ O)
{
    __shared__ __align__(16) bf16_t Kt[64][136];   // [key][d], padded (2-way banks)
    __shared__ __align__(16) bf16_t Vt[128][72];   // transposed [d][key], padded
    __shared__ __align__(16) bf16_t Pl[8][16][72]; // per-wave P transform buffer

    const int qb = 15 - blockIdx.x;                // heavy blocks first (LPT)
    const int h = blockIdx.y, b = blockIdx.z;
    const int tid = threadIdx.x, wave = tid >> 6, lane = tid & 63;
    const int lrow = lane & 15, quad = lane >> 4;
    const int q0 = qb * 128 + wave * 16;           // this wave's first Q row

    // Q fragments: 16 rows x D=128 (4 K-steps of 32), held in regs
    bf16x8 qf[4];
    {
        const bf16_t* qp = Q + ((size_t)(b * S_ + q0 + lrow)) * E_ + h * D_ + quad * 8;
#pragma unroll
        for (int ks = 0; ks < 4; ++ks) qf[ks] = *(const bf16x8*)(qp + ks * 32);
    }

    f32x4 oacc[8] = {};
    float rs[4] = {0.f, 0.f, 0.f, 0.f};

    const int ntiles = 2 * qb + 2;
    for (int kt = 0; kt < ntiles; ++kt) {
        const int k_base = kt * 64;
        __syncthreads();   // prior iteration's Kt/Vt reads complete
        // stage K-tile 64x128: coalesced 16B chunks, 2 per thread
#pragma unroll
        for (int i = 0; i < 2; ++i) {
            int c = tid + 512 * i;
            int row = c >> 4, cc = (c & 15) << 3;
            *(uint4*)&Kt[row][cc] =
                *(const uint4*)(KV + ((size_t)(b * S_ + k_base + row)) * 256 + cc);
        }
        // stage V-tile transposed: lane-consecutive keys -> conflict-free LDS writes
#pragma unroll
        for (int i = 0; i < 2; ++i) {
            int c = tid + 512 * i;
            int n = c & 63, d0 = (c >> 6) << 3;
            bf16x8 v = *(const bf16x8*)(KV + ((size_t)(b * S_ + k_base + n)) * 256 + 128 + d0);
#pragma unroll
            for (int j = 0; j < 8; ++j) Vt[d0 + j][n] = v[j];
        }
        __syncthreads();

        if (k_base <= q0 + 15) {   // wave skips fully-masked tiles (still hits barriers)
            // S = Q K^T : 16x64
            f32x4 sc[4] = {};
#pragma unroll
            for (int ks = 0; ks < 4; ++ks) {
                bf16x8 a = qf[ks];
#pragma unroll
                for (int c = 0; c < 4; ++c) {
                    bf16x8 kb = *(const bf16x8*)&Kt[c * 16 + lrow][ks * 32 + quad * 8];
                    sc[c] = __builtin_amdgcn_mfma_f32_16x16x32_bf16(a, kb, sc[c], 0, 0, 0);
                }
            }
            const bool diag = (k_base + 63 > q0);
#pragma unroll
            for (int c = 0; c < 4; ++c) {
#pragma unroll
                for (int r = 0; r < 4; ++r) {
                    float s = sc[c][r];   // already in log2 domain (Q pre-scaled)
                    if (diag) {
                        int kj = k_base + c * 16 + lrow;
                        int qi = q0 + quad * 4 + r;
                        if (kj > qi) s = -1e30f;
                    }
                    float p = exp2f(fminf(s, 110.f));
                    rs[r] += p;
                    Pl[wave][quad * 4 + r][c * 16 + lrow] = (bf16_t)p;
                }
            }
            // Pl is per-wave: no barrier needed (compiler orders ds_write->ds_read)
#pragma unroll
            for (int ks = 0; ks < 2; ++ks) {
                bf16x8 ap = *(const bf16x8*)&Pl[wave][lrow][ks * 32 + quad * 8];
#pragma unroll
                for (int dt = 0; dt < 8; ++dt) {
                    bf16x8 bv = *(const bf16x8*)&Vt[dt * 16 + lrow][ks * 32 + quad * 8];
                    oacc[dt] = __builtin_amdgcn_mfma_f32_16x16x32_bf16(ap, bv, oacc[dt], 0, 0, 0);
                }
            }
        }
    }

    // epilogue: one shuffle-reduction of row sums, normalize, store
#pragma unroll
    for (int off = 8; off >= 1; off >>= 1)
#pragma unroll
        for (int r = 0; r < 4; ++r) rs[r] += __shfl_xor(rs[r], off, 16);
#pragma unroll
    for (int r = 0; r < 4; ++r) {
        float inv = 1.0f / rs[r];
        int row = q0 + quad * 4 + r;
#pragma unroll
        for (int dt = 0; dt < 8; ++dt)
            O[((size_t)(b * S_ + row)) * E_ + h * D_ + dt * 16 + lrow] =
                (bf16_t)(oacc[dt][r] * inv);
    }
}

// ---------------- launch ----------------
extern "C" void kernel_launch(void* const* d_in, const int* in_sizes, int n_in,
                              void* d_out, int out_size, void* d_ws, size_t ws_size,
                              hipStream_t stream)
{
    const float* x   = (const float*)d_in[0];
    const float* kv  = (const float*)d_in[1];
    const float* Wq  = (const float*)d_in[2];
    const float* bq  = (const float*)d_in[3];
    const float* Wk  = (const float*)d_in[4];
    const float* bk  = (const float*)d_in[5];
    const float* Wv  = (const float*)d_in[6];
    const float* bv  = (const float*)d_in[7];
    const float* Wo  = (const float*)d_in[8];
    const float* bo  = (const float*)d_in[9];
    float* out = (float*)d_out;

    bf16_t* p    = (bf16_t*)d_ws;
    bf16_t* xb   = p;  p += (size_t)BS_ * E_;
    bf16_t* kvb  = p;  p += (size_t)BS_ * E_;
    bf16_t* Wqb  = p;  p += (size_t)E_ * E_;
    bf16_t* Wkvb = p;  p += (size_t)2 * D_ * E_;   // Wk rows then Wv rows, contiguous
    bf16_t* Wob  = p;  p += (size_t)E_ * E_;
    bf16_t* Qb   = p;  p += (size_t)BS_ * E_;
    bf16_t* KVb  = p;  p += (size_t)BS_ * 256;     // interleaved [row][K|V]
    bf16_t* Ob   = p;  p += (size_t)BS_ * E_;

    // one fused convert kernel (6 segments, compile-time prefix sums)
    cvt_all<<<dim3(25088), dim3(256), 0, stream>>>(
        x, kv, Wq, Wk, Wv, Wo,
        xb, kvb, Wqb, Wkvb, Wkvb + (size_t)D_ * E_, Wob);

    // Q projection, scale folded in (exp2-domain attention)
    gemm_bt<<<dim3(E_ / 128, BS_ / 128), 256, 0, stream>>>(
        xb, Wqb, bq, nullptr, nullptr, Qb, BS_, E_, E_, QSCALE);
    // fused K+V projection -> interleaved KV buffer
    gemm_bt<<<dim3(2, BS_ / 128), 256, 0, stream>>>(
        kvb, Wkvb, bk, bv, nullptr, KVb, BS_, 256, E_, 1.0f);

    // attention
    mqa_attn<<<dim3(S_ / 128, H_, B_), 512, 0, stream>>>(Qb, KVb, Ob);

    // output projection (fp32 out)
    gemm_bt<<<dim3(E_ / 128, BS_ / 128), 256, 0, stream>>>(
        Ob, Wob, bo, nullptr, out, nullptr, BS_, E_, E_, 1.0f);
}

// Round 3
// 365.735 us; speedup vs baseline: 1.4261x; 1.1652x over previous
//
#include <hip/hip_runtime.h>

#define B_  2
#define S_  2048
#define E_  2048
#define H_  16
#define D_  128
#define BS_ (B_*S_)

typedef __bf16 bf16_t;
typedef __bf16 bf16x8 __attribute__((ext_vector_type(8)));
typedef __bf16 bf16x4 __attribute__((ext_vector_type(4)));
typedef float  f32x4  __attribute__((ext_vector_type(4)));

// combined softmax scale: 1/sqrt(128) * log2(e), folded into Q projection
#define QSCALE 0.1275174131003543f

// ---------------- async global->LDS, 16B per lane per call ----------------
__device__ __forceinline__ void gld16(const bf16_t* g, bf16_t* l) {
    __builtin_amdgcn_global_load_lds(
        (const __attribute__((address_space(1))) void*)g,
        (__attribute__((address_space(3))) void*)l,
        16, 0, 0);
}

// ---------------- fused fp32 -> bf16 convert (all 6 tensors) ----------------
__global__ void cvt_all(const float* __restrict__ s0, const float* __restrict__ s1,
                        const float* __restrict__ s2, const float* __restrict__ s3,
                        const float* __restrict__ s4, const float* __restrict__ s5,
                        bf16_t* d0, bf16_t* d1, bf16_t* d2,
                        bf16_t* d3, bf16_t* d4, bf16_t* d5)
{
    long i = ((long)blockIdx.x * blockDim.x + threadIdx.x) * 4;
    const float* s; bf16_t* d;
    if      (i <  8388608) { s = s0; d = d0; }
    else if (i < 16777216) { s = s1; d = d1; i -=  8388608; }
    else if (i < 20971520) { s = s2; d = d2; i -= 16777216; }
    else if (i < 21233664) { s = s3; d = d3; i -= 20971520; }
    else if (i < 21495808) { s = s4; d = d4; i -= 21233664; }
    else                   { s = s5; d = d5; i -= 21495808; }
    float4 v = *(const float4*)(s + i);
    bf16x4 o;
    o[0] = (bf16_t)v.x; o[1] = (bf16_t)v.y; o[2] = (bf16_t)v.z; o[3] = (bf16_t)v.w;
    *(bf16x4*)(d + i) = o;
}

// ============= GEMM core (m97 structure) as a macro-able inline =============
// computes a 128x128 tile of (A[M,K] @ W[N,K]^T + bias) * scale
__device__ __forceinline__ void gemm_tile(
    const bf16_t* __restrict__ A, const bf16_t* __restrict__ W,
    const float* __restrict__ biasA, const float* __restrict__ biasB,
    float* __restrict__ Cf, bf16_t* __restrict__ Cb,
    int N, int K, float scale, int m0, int n0,
    bf16_t* As, bf16_t* Bs)
{
    const int tid  = threadIdx.x;
    const int wave = tid >> 6, lane = tid & 63;
    const int wm = wave >> 1, wn = wave & 1;
    const int lrow = lane & 15, quad = lane >> 4;
    const int r8 = lane >> 3, c8 = (lane & 7) << 3;

    f32x4 acc[4][4] = {};

    for (int k0 = 0; k0 < K; k0 += 64) {
        __syncthreads();
#pragma unroll
        for (int j = 0; j < 4; ++j) {
            int base = (wave * 4 + j) * 8;
            gld16(A + (size_t)(m0 + base + r8) * K + k0 + c8, &As[base * 64]);
            gld16(W + (size_t)(n0 + base + r8) * K + k0 + c8, &Bs[base * 64]);
        }
        __syncthreads();
#pragma unroll
        for (int ks = 0; ks < 2; ++ks) {
            bf16x8 af[4], bfr[4];
#pragma unroll
            for (int mt = 0; mt < 4; ++mt)
                af[mt] = *(const bf16x8*)&As[(wm * 64 + mt * 16 + lrow) * 64 + ks * 32 + quad * 8];
#pragma unroll
            for (int nt = 0; nt < 4; ++nt)
                bfr[nt] = *(const bf16x8*)&Bs[(wn * 64 + nt * 16 + lrow) * 64 + ks * 32 + quad * 8];
#pragma unroll
            for (int mt = 0; mt < 4; ++mt)
#pragma unroll
                for (int nt = 0; nt < 4; ++nt)
                    acc[mt][nt] = __builtin_amdgcn_mfma_f32_16x16x32_bf16(
                        af[mt], bfr[nt], acc[mt][nt], 0, 0, 0);
        }
    }

#pragma unroll
    for (int mt = 0; mt < 4; ++mt) {
#pragma unroll
        for (int nt = 0; nt < 4; ++nt) {
            int col = n0 + wn * 64 + nt * 16 + lrow;
            const float* bp = biasA; int ci = col;
            if (biasB && col >= 128) { bp = biasB; ci = col - 128; }
            float bv = bp[ci];
#pragma unroll
            for (int r = 0; r < 4; ++r) {
                int row = m0 + wm * 64 + mt * 16 + quad * 4 + r;
                float v = (acc[mt][nt][r] + bv) * scale;
                if (Cf) Cf[(size_t)row * N + col] = v;
                else    Cb[(size_t)row * N + col] = (bf16_t)v;
            }
        }
    }
}

// ---------------- fused Q + KV projection ----------------
// grid (18, 32): bx<16 -> Q-proj col-tile bx (N=2048, scale=QSCALE),
//                bx>=16 -> KV-proj col-tile bx-16 (N=256, dual bias)
__global__ __launch_bounds__(256) void gemm_qkv(
    const bf16_t* __restrict__ xb, const bf16_t* __restrict__ kvb,
    const bf16_t* __restrict__ Wq, const bf16_t* __restrict__ Wkv,
    const float* __restrict__ bq, const float* __restrict__ bk,
    const float* __restrict__ bv,
    bf16_t* __restrict__ Qb, bf16_t* __restrict__ KVb)
{
    __shared__ __align__(16) bf16_t As[128 * 64];
    __shared__ __align__(16) bf16_t Bs[128 * 64];
    const int m0 = blockIdx.y * 128;
    if (blockIdx.x < 16) {
        gemm_tile(xb, Wq, bq, nullptr, nullptr, Qb, E_, E_, QSCALE,
                  m0, blockIdx.x * 128, As, Bs);
    } else {
        gemm_tile(kvb, Wkv, bk, bv, nullptr, KVb, 256, E_, 1.0f,
                  m0, (blockIdx.x - 16) * 128, As, Bs);
    }
}

// ---------------- O projection (fp32 out) ----------------
__global__ __launch_bounds__(256) void gemm_o(
    const bf16_t* __restrict__ A, const bf16_t* __restrict__ W,
    const float* __restrict__ bias, float* __restrict__ Cf)
{
    __shared__ __align__(16) bf16_t As[128 * 64];
    __shared__ __align__(16) bf16_t Bs[128 * 64];
    gemm_tile(A, W, bias, nullptr, Cf, nullptr, E_, E_, 1.0f,
              blockIdx.y * 128, blockIdx.x * 128, As, Bs);
}

// ---------------- flash-style causal MQA attention ----------------
// Q pre-scaled by 1/sqrt(D)*log2(e); KV interleaved [B,S,128K|128V] bf16.
// 512 threads = 8 waves, 128 Q rows per block.
// Complementary qb pairing: co-resident blocks (i, i+256) differ only in
// blockIdx.z, so qb = z ? bx : 15-bx gives every CU a (heavy, light) pair
// with constant total load (36 tiles).
// Register-pipelined staging: tile t+1's K/V prefetched into VGPRs during
// tile t's compute; barrier only drains loads issued a full tile earlier.
__global__ __launch_bounds__(512, 4) void mqa_attn(
    const bf16_t* __restrict__ Q, const bf16_t* __restrict__ KV,
    bf16_t* __restrict__ O)
{
    __shared__ __align__(16) bf16_t Kt[64][136];   // [key][d], stride 68 dw (2-way free)
    __shared__ __align__(16) bf16_t Vt[128][72];   // [d][key], stride 36 dw (2-way free)
    __shared__ __align__(16) bf16_t Pl[8][16][72]; // per-wave P C->A layout bounce

    const int bx = blockIdx.x, h = blockIdx.y, b = blockIdx.z;
    const int qb = b ? bx : (15 - bx);             // complementary pairing
    const int tid = threadIdx.x, wave = tid >> 6, lane = tid & 63;
    const int lrow = lane & 15, quad = lane >> 4;
    const int q0 = qb * 128 + wave * 16;

    const bf16_t* kvp = KV + (size_t)(b * S_) * 256;

    // Q fragments: 16 rows x D=128, in regs
    bf16x8 qf[4];
    {
        const bf16_t* qp = Q + ((size_t)(b * S_ + q0 + lrow)) * E_ + h * D_ + quad * 8;
#pragma unroll
        for (int ks = 0; ks < 4; ++ks) qf[ks] = *(const bf16x8*)(qp + ks * 32);
    }

    f32x4 oacc[8] = {};
    float rs[4] = {0.f, 0.f, 0.f, 0.f};

    const int ntiles = 2 * qb + 2;
    bf16x8 kreg[2], vreg[2];

    // preload tile 0
#pragma unroll
    for (int i = 0; i < 2; ++i) {
        int c = tid + 512 * i;
        kreg[i] = *(const bf16x8*)(kvp + (size_t)(c >> 4) * 256 + ((c & 15) << 3));
        vreg[i] = *(const bf16x8*)(kvp + (size_t)(c & 63) * 256 + 128 + ((c >> 6) << 3));
    }

    for (int kt = 0; kt < ntiles; ++kt) {
        const int k_base = kt * 64;
        __syncthreads();   // prior iteration's LDS reads done (also drains prefetch vmcnt)
        // regs -> LDS
#pragma unroll
        for (int i = 0; i < 2; ++i) {
            int c = tid + 512 * i;
            *(bf16x8*)&Kt[c >> 4][(c & 15) << 3] = kreg[i];
            int n = c & 63, d0 = (c >> 6) << 3;
#pragma unroll
            for (int j = 0; j < 8; ++j) Vt[d0 + j][n] = vreg[i][j];
        }
        __syncthreads();
        // issue prefetch for tile kt+1 (completes during this tile's compute)
        if (kt + 1 < ntiles) {
            const int nb = (kt + 1) * 64;
#pragma unroll
            for (int i = 0; i < 2; ++i) {
                int c = tid + 512 * i;
                kreg[i] = *(const bf16x8*)(kvp + (size_t)(nb + (c >> 4)) * 256 + ((c & 15) << 3));
                vreg[i] = *(const bf16x8*)(kvp + (size_t)(nb + (c & 63)) * 256 + 128 + ((c >> 6) << 3));
            }
        }

        if (k_base <= q0 + 15) {   // wave skips fully-masked tiles
            // S = Q K^T : 16x64
            f32x4 sc[4] = {};
#pragma unroll
            for (int ks = 0; ks < 4; ++ks) {
                bf16x8 a = qf[ks];
#pragma unroll
                for (int c = 0; c < 4; ++c) {
                    bf16x8 kb = *(const bf16x8*)&Kt[c * 16 + lrow][ks * 32 + quad * 8];
                    sc[c] = __builtin_amdgcn_mfma_f32_16x16x32_bf16(a, kb, sc[c], 0, 0, 0);
                }
            }
            const bool diag = (k_base + 63 > q0);
#pragma unroll
            for (int c = 0; c < 4; ++c) {
#pragma unroll
                for (int r = 0; r < 4; ++r) {
                    float s = sc[c][r];   // log2 domain (Q pre-scaled)
                    if (diag) {
                        int kj = k_base + c * 16 + lrow;
                        int qi = q0 + quad * 4 + r;
                        if (kj > qi) s = -1e30f;
                    }
                    float p = exp2f(fminf(s, 110.f));
                    rs[r] += p;
                    Pl[wave][quad * 4 + r][c * 16 + lrow] = (bf16_t)p;
                }
            }
            // per-wave buffer: compiler orders ds_write->ds_read via lgkmcnt
#pragma unroll
            for (int ks = 0; ks < 2; ++ks) {
                bf16x8 ap = *(const bf16x8*)&Pl[wave][lrow][ks * 32 + quad * 8];
#pragma unroll
                for (int dt = 0; dt < 8; ++dt) {
                    bf16x8 bv = *(const bf16x8*)&Vt[dt * 16 + lrow][ks * 32 + quad * 8];
                    oacc[dt] = __builtin_amdgcn_mfma_f32_16x16x32_bf16(ap, bv, oacc[dt], 0, 0, 0);
                }
            }
        }
    }

    // epilogue: one shuffle-reduction of row sums, normalize, store
#pragma unroll
    for (int off = 8; off >= 1; off >>= 1)
#pragma unroll
        for (int r = 0; r < 4; ++r) rs[r] += __shfl_xor(rs[r], off, 16);
#pragma unroll
    for (int r = 0; r < 4; ++r) {
        float inv = 1.0f / rs[r];
        int row = q0 + quad * 4 + r;
#pragma unroll
        for (int dt = 0; dt < 8; ++dt)
            O[((size_t)(b * S_ + row)) * E_ + h * D_ + dt * 16 + lrow] =
                (bf16_t)(oacc[dt][r] * inv);
    }
}

// ---------------- launch ----------------
extern "C" void kernel_launch(void* const* d_in, const int* in_sizes, int n_in,
                              void* d_out, int out_size, void* d_ws, size_t ws_size,
                              hipStream_t stream)
{
    const float* x   = (const float*)d_in[0];
    const float* kv  = (const float*)d_in[1];
    const float* Wq  = (const float*)d_in[2];
    const float* bq  = (const float*)d_in[3];
    const float* Wk  = (const float*)d_in[4];
    const float* bk  = (const float*)d_in[5];
    const float* Wv  = (const float*)d_in[6];
    const float* bv  = (const float*)d_in[7];
    const float* Wo  = (const float*)d_in[8];
    const float* bo  = (const float*)d_in[9];
    float* out = (float*)d_out;

    bf16_t* p    = (bf16_t*)d_ws;
    bf16_t* xb   = p;  p += (size_t)BS_ * E_;
    bf16_t* kvb  = p;  p += (size_t)BS_ * E_;
    bf16_t* Wqb  = p;  p += (size_t)E_ * E_;
    bf16_t* Wkvb = p;  p += (size_t)2 * D_ * E_;
    bf16_t* Wob  = p;  p += (size_t)E_ * E_;
    bf16_t* Qb   = p;  p += (size_t)BS_ * E_;
    bf16_t* KVb  = p;  p += (size_t)BS_ * 256;
    bf16_t* Ob   = p;  p += (size_t)BS_ * E_;

    cvt_all<<<dim3(25088), dim3(256), 0, stream>>>(
        x, kv, Wq, Wk, Wv, Wo,
        xb, kvb, Wqb, Wkvb, Wkvb + (size_t)D_ * E_, Wob);

    // fused Q + KV projections
    gemm_qkv<<<dim3(18, BS_ / 128), 256, 0, stream>>>(
        xb, kvb, Wqb, Wkvb, bq, bk, bv, Qb, KVb);

    // attention
    mqa_attn<<<dim3(S_ / 128, H_, B_), 512, 0, stream>>>(Qb, KVb, Ob);

    // output projection (fp32 out)
    gemm_o<<<dim3(E_ / 128, BS_ / 128), 256, 0, stream>>>(Ob, Wob, bo, out);
}